// Round 14
// baseline (116.066 us; speedup 1.0000x reference)
//
#include <hip/hip_runtime.h>

#define CC 8
#define KK 64
#define BB 8192
#define NCHUNK 16
#define NGBLK (NCHUNK * CC)            // 128 gram blocks
#define ROWS_PER_CHUNK (BB / NCHUNK)   // 512

// ---------------- workspace layout (bytes) -----------------------------------------------
// [0 .. OFF_GFST) zeroed by memset 1; gfirst set to 0x7f7f7f7f by memset 2.
#define OFF_G     0                    // f64 G[8][4096]   = 262144 (atomic-accumulated)
#define OFF_GSUM  262144               // f32 gsum[8][64]  =   2048 (atomic-accumulated)
#define OFF_GCNT  264192               // int gcount[8]    =     32
#define OFF_CNTR  264224               // int term counter =      4
#define OFF_FLG   264228               // int X ready flag =      4
#define OFF_DONE  264232               // int gram done    =      4 (+4 pad)
#define OFF_GFST  264240               // int gfirst[8]    =     32 (0x7f = +inf for atomicMin)
#define OFF_X     264272               // f64 Xg[4096]     =  32768
#define OFF_LD2   297040               // f64 logdet_total =      8
#define OFF_TERMS 297048               // f64 terms[8]     =     64

// ---------------- worker LDS layout (double indices) -------------------------------------
#define SM_BUFA  0                     // [64][65] Sigma -> in-place chol; Xs overlays after
#define SM_SPART 4160                  // solve partials [4][8][64] = 2048
#define SM_PANEL 8320                  // wred[8] (combine scratch)
#define SM_LB    8832                  // [64][65] class: Sigma_c stash | blk8: normalized L
#define SM_LDI   12992                 // [64]     class: dv            | blk8: 1/L[i][i]
#define SM_MB    13056                 // [64]     mean
#define SM_INTS  13120                 // 16 ints: cnt8s[8], fst8s[8]
#define SMEM_N   13128

__device__ __forceinline__ double readlane_f64(double v, int lane) {
  union { double d; int i[2]; } u, r;
  u.d = v;
  r.i[0] = __builtin_amdgcn_readlane(u.i[0], lane);
  r.i[1] = __builtin_amdgcn_readlane(u.i[1], lane);
  return r.d;
}
__device__ __forceinline__ double aload_f64(const double* p) {
  return __hip_atomic_load(p, __ATOMIC_RELAXED, __HIP_MEMORY_SCOPE_AGENT);
}
__device__ __forceinline__ float aload_f32(const float* p) {
  return __hip_atomic_load(p, __ATOMIC_RELAXED, __HIP_MEMORY_SCOPE_AGENT);
}
__device__ __forceinline__ int aload_i32(const int* p) {
  return __hip_atomic_load(p, __ATOMIC_RELAXED, __HIP_MEMORY_SCOPE_AGENT);
}

// ========== 4-wave blocked Cholesky: in-place, readlane trailing, 8 barriers ==========
__device__ __noinline__ double chol64(double* smem, bool isS2) {
  int tid = threadIdx.x;
  int t = tid & 63, w = tid >> 6;
  double (*A)[KK + 1] = (double (*)[KK + 1])(smem + SM_BUFA);
  double (*Lb)[KK + 1] = (double (*)[KK + 1])(smem + SM_LB);
  double* Ldi = smem + SM_LDI;
  double ldacc = 0.0;
  int bound = t | 7;
#pragma unroll 1
  for (int p = 0; p < 8; ++p) {
    const int P0 = p * 8;
    double cc_[8];
#pragma unroll
    for (int m = 0; m < 8; ++m) cc_[m] = A[t][P0 + m];
    double uu[8];
    double pd = 1.0;
#pragma unroll
    for (int m = 0; m < 8; ++m) {
      double akk = readlane_f64(cc_[m], P0 + m);   // uniform SGPR lane -> v_readlane
      pd *= akk;
      double inv;
      asm("v_rcp_f64 %0, %1" : "=v"(inv) : "v"(akk));
      inv = inv * fma(-akk, inv, 2.0);             // 1 Newton: rel err ~4e-9
      uu[m] = cc_[m] * inv;
      if (isS2 && w == 0) {
        double rsv = sqrt(akk) * inv;              // 1/sqrt(akk)
        Lb[t][P0 + m] = cc_[m] * rsv;
        if (t == 0) Ldi[P0 + m] = rsv;
      }
#pragma unroll
      for (int mm = m + 1; mm < 8; ++mm)
        cc_[mm] -= uu[m] * readlane_f64(cc_[m], P0 + mm);
    }
    ldacc += log(pd);
#pragma unroll 1
    for (int jb = p + 1 + w; jb < 8; jb += 4) {    // wave-split trailing, panel via readlane
      int j = jb * 8;
      if (j <= bound) {
        double aj[8];
#pragma unroll
        for (int q = 0; q < 8; ++q) aj[q] = A[t][j + q];
#pragma unroll
        for (int m = 0; m < 8; ++m) {
          double u = uu[m];
#pragma unroll
          for (int q = 0; q < 8; ++q)
            aj[q] -= u * readlane_f64(cc_[m], j + q);
        }
#pragma unroll
        for (int q = 0; q < 8; ++q) A[t][j + q] = aj[q];
      }
    }
    __syncthreads();
  }
  return ldacc;
}

// ================= single fused kernel: 128 gram blocks + 9 worker blocks ================
__global__ __launch_bounds__(256) void k_all(const float* __restrict__ mu,
                                             const int* __restrict__ labels,
                                             const float* __restrict__ cov,
                                             float* out, char* ws) {
  __shared__ double smem[SMEM_N];
  int blk = blockIdx.x;
  int tid = threadIdx.x;
  int t = tid & 63, w = tid >> 6;
  double* G = (double*)(ws + OFF_G);
  float* gsum = (float*)(ws + OFF_GSUM);
  int* gcount = (int*)(ws + OFF_GCNT);
  int* gfirst = (int*)(ws + OFF_GFST);
  double* Xg = (double*)(ws + OFF_X);
  double* ld2g = (double*)(ws + OFF_LD2);
  double* terms = (double*)(ws + OFF_TERMS);
  int* cntr = (int*)(ws + OFF_CNTR);
  int* flg = (int*)(ws + OFF_FLG);
  int* done = (int*)(ws + OFF_DONE);

  if (blk < NGBLK) {
    // ===================== gram + stats (R13 k_front, unchanged core) ====================
    int chunk = blk >> 3, c = blk & 7;
    int lane = tid & 63;
    int tx = tid & 15, ty = tid >> 4;
    float* rows = (float*)smem;
    int* labs = (int*)(smem + 2048);
    float* ssum = (float*)(smem + 2080);
    int* scnt = (int*)(smem + 2112);
    int* sfst = (int*)(smem + 2114);

    double acc[4][4] = {{0.0}};
    float rsum = 0.f;
    int cnt = 0, first = BB;
    int base = chunk * ROWS_PER_CHUNK;
    const float4* mu4 = (const float4*)mu + (size_t)base * (KK / 4);
    if (tid < KK) ssum[tid] = 0.f;

    float4 pf[4];
    int plab = 0;
#pragma unroll
    for (int i = 0; i < 4; ++i) pf[i] = mu4[tid + i * 256];
    if (tid < 64) plab = labels[base + tid];

#pragma unroll 1
    for (int g = 0; g < ROWS_PER_CHUNK / 64; ++g) {
      __syncthreads();
      float4* rows4 = (float4*)rows;
#pragma unroll
      for (int i = 0; i < 4; ++i) rows4[tid + i * 256] = pf[i];
      if (tid < 64) labs[tid] = plab;
      __syncthreads();
      if (g + 1 < ROWS_PER_CHUNK / 64) {
#pragma unroll
        for (int i = 0; i < 4; ++i) pf[i] = mu4[(g + 1) * 1024 + tid + i * 256];
        if (tid < 64) plab = labels[base + (g + 1) * 64 + tid];
      }
#pragma unroll 4
      for (int r = 0; r < 16; ++r) {
        int rr = w * 16 + r;
        if (labs[rr] == c) rsum += rows[rr * KK + lane];
      }
      if (lane < 16 && labs[w * 16 + lane] == c) {
        cnt++;
        first = min(first, base + g * 64 + w * 16 + lane);
      }
      unsigned long long m = __ballot(labs[lane] == c);
      while (m) {
        int r = __builtin_ctzll(m);
        m &= m - 1;
        const float4* rw4 = (const float4*)(rows + r * KK);
        float4 a4 = rw4[ty], b4 = rw4[tx];
        const float* ai = (const float*)&a4;
        const float* bj = (const float*)&b4;
#pragma unroll
        for (int a = 0; a < 4; ++a)
#pragma unroll
          for (int b = 0; b < 4; ++b) acc[a][b] += (double)ai[a] * (double)bj[b];
      }
    }
    double* Gc = G + (size_t)c * KK * KK;
#pragma unroll
    for (int a = 0; a < 4; ++a)
#pragma unroll
      for (int b = 0; b < 4; ++b)
        atomicAdd(&Gc[(ty * 4 + a) * KK + tx * 4 + b], acc[a][b]);
    atomicAdd(&ssum[lane], rsum);
#pragma unroll
    for (int off = 32; off; off >>= 1) {
      cnt += __shfl_down(cnt, off);
      first = min(first, __shfl_down(first, off));
    }
    if (lane == 0) { scnt[w] = cnt; sfst[w] = first; }
    __syncthreads();
    if (tid < KK) {
      float v = ssum[tid];
      if (v != 0.f) atomicAdd(&gsum[c * KK + tid], v);
    }
    if (tid == 0) {
      int ct = scnt[0] + scnt[1] + scnt[2] + scnt[3];
      if (ct) {
        atomicAdd(&gcount[c], ct);
        atomicMin(&gfirst[c], min(min(sfst[0], sfst[1]), min(sfst[2], sfst[3])));
      }
    }
    __syncthreads();                     // all lanes' atomics drained (vmcnt) before signal
    if (tid == 0) {
      __threadfence();
      atomicAdd(done, 1);                // publish this block's contributions
    }
    return;
  }

  // ======================= workers: wait for all gram blocks ==============================
  if (tid == 0) {
    int it = 0;
    while (__hip_atomic_load(done, __ATOMIC_ACQUIRE, __HIP_MEMORY_SCOPE_AGENT) < NGBLK &&
           ++it < (1 << 22))
      __builtin_amdgcn_s_sleep(8);
  }
  __syncthreads();

  double* mb = smem + SM_MB;
  int* cnt8s = (int*)(smem + SM_INTS);
  int* fst8s = cnt8s + 8;

  if (blk < NGBLK + CC) {
    // ================================ class block ========================================
    int c = blk - NGBLK;
    if (tid < 64) {
      double st = 0.0;
#pragma unroll
      for (int cc2 = 0; cc2 < CC; ++cc2) st += (double)aload_f32(&gsum[cc2 * KK + t]);
      smem[SM_LDI + t] = st * (1.0 / (double)BB);     // mtot (temp)
      smem[SM_MB + t] = (double)aload_f32(&gsum[c * KK + t]);
    } else if (tid < 80) {
      int j = tid - 64;
      if (j < 8) cnt8s[j] = aload_i32(&gcount[j]);
      else fst8s[j - 8] = aload_i32(&gfirst[j - 8]);
    }
    __syncthreads();
    int nc = cnt8s[c];
    double ncd = (double)nc;
    double safe = nc > 0 ? ncd : 1.0;
    double inv_safe = 1.0 / safe;
    if (tid < 64) {
      double m = smem[SM_MB + t] * inv_safe;
      smem[SM_MB + t] = m;
      smem[SM_LDI + t] -= m;                          // dv = mtot - mean
    }
    __syncthreads();

    // build Sigma_c into bufA + stash (G via atomic loads: in-kernel cross-block data)
    double* stash = smem + SM_LB;
    const double* Gc = G + (size_t)c * KK * KK;
#pragma unroll
    for (int q = 0; q < 16; ++q) {
      int e = tid + q * 256;
      int r = e >> 6, c0 = e & 63;
      double v = (double)cov[e] + (aload_f64(&Gc[e]) - ncd * mb[r] * mb[c0]) * inv_safe;
      smem[SM_BUFA + r * (KK + 1) + c0] = v;
      stash[r * (KK + 1) + c0] = v;
    }
    __syncthreads();

    double ld1 = chol64(smem, false);                 // overlaps block 8's build/chol/solve

    if (tid == 0) {
      int it = 0;
      while (__hip_atomic_load(flg, __ATOMIC_ACQUIRE, __HIP_MEMORY_SCOPE_AGENT) == 0 &&
             ++it < (1 << 22))
        __builtin_amdgcn_s_sleep(8);
    }
    __syncthreads();
    double ld2 = aload_f64(ld2g);

    // on-the-fly xtx+combine: acc_r = sum_k X[k][r]*X[k][t] via reg-cached own column
    double* dvv = smem + SM_LDI;
    double s[16];
#pragma unroll
    for (int rr = 0; rr < 16; ++rr) s[rr] = 0.0;
#pragma unroll 1
    for (int half = 0; half < 2; ++half) {
      double xt[32];
      int kb = half * 32;
#pragma unroll
      for (int kk = 0; kk < 32; ++kk) xt[kk] = aload_f64(&Xg[(kb + kk) * KK + t]);  // coalesced
#pragma unroll 1
      for (int rr = 0; rr < 16; ++rr) {
        int r = w + rr * 4;                           // uniform per wave
        double acc2 = 0.0;
#pragma unroll
        for (int kk = 0; kk < 32; ++kk)
          acc2 += readlane_f64(xt[kk], r) * xt[kk];   // zeros handle triangular bounds
        s[rr] += acc2;
      }
    }
    double trp = 0.0, qp = 0.0;
#pragma unroll
    for (int rr = 0; rr < 16; ++rr) {
      int r = w + rr * 4;
      trp += s[rr] * stash[r * (KK + 1) + t];
      qp += s[rr] * dvv[r];
    }
    qp *= dvv[t];
#pragma unroll
    for (int m = 32; m; m >>= 1) {
      trp += __shfl_down(trp, m);
      qp += __shfl_down(qp, m);
    }
    double* wred = smem + SM_PANEL;
    if (t == 0) { wred[w * 2] = trp; wred[w * 2 + 1] = qp; }
    __syncthreads();
    if (tid == 0) {
      double tr = wred[0] + wred[2] + wred[4] + wred[6];
      double quad = wred[1] + wred[3] + wred[5] + wred[7];
      int best = 0;
      long long bv = -2;
      for (int j = 0; j < CC; ++j) {
        long long v = cnt8s[j] > 0 ? (long long)fst8s[j] : -1;
        if (v > bv) { bv = v; best = j; }             // strict > == argmax tie-break
      }
      double kl = 0.5 * (tr + quad - (double)KK + ld2 - ld1);
      double wgt = (nc > 0 && c != best) ? ncd : 0.0;
      double term = kl * wgt / (double)BB;
      atomicExch((unsigned long long*)&terms[c],
                 (unsigned long long)__double_as_longlong(term));
      __threadfence();
      int old = atomicAdd(cntr, 1);
      if (old == CC - 1) {                            // last arriver gathers + writes
        double sres = 0.0;
        for (int j = 0; j < CC; ++j) sres += atomicAdd(&terms[j], 0.0);
        out[0] = (float)sres;
      }
    }
  } else {
    // ================================ block 8 (total) ====================================
    if (tid < 64) {
      double st = 0.0;
#pragma unroll
      for (int cc2 = 0; cc2 < CC; ++cc2) st += (double)aload_f32(&gsum[cc2 * KK + t]);
      mb[t] = st * (1.0 / (double)BB);
    }
    __syncthreads();
    const double invB = 1.0 / (double)BB;
#pragma unroll 1
    for (int q = 0; q < 16; ++q) {
      int e = tid + q * 256;
      double g = 0.0;
#pragma unroll
      for (int c2 = 0; c2 < CC; ++c2) g += aload_f64(&G[(size_t)c2 * KK * KK + e]);
      int r = e >> 6, c0 = e & 63;
      smem[SM_BUFA + r * (KK + 1) + c0] = (double)cov[e] + g * invB - mb[r] * mb[c0];
    }
    __syncthreads();
    double ld2 = chol64(smem, true);

    // X = L^{-1}: 4-wave striped partials, wave-0 finish per group of 8
    double (*Xs)[KK] = (double (*)[KK])(smem + SM_BUFA);
    double (*Lb)[KK + 1] = (double (*)[KK + 1])(smem + SM_LB);
    double* Ldi = smem + SM_LDI;
    double* spart = smem + SM_SPART;
#pragma unroll 1
    for (int g = 0; g < 8; ++g) {
      int I0 = g * 8;
      double sv[8];
#pragma unroll
      for (int m = 0; m < 8; ++m) sv[m] = 0.0;
#pragma unroll 1
      for (int j = w; j < I0; j += 4) {
        double xj = Xs[j][t];
#pragma unroll
        for (int m = 0; m < 8; ++m) sv[m] += Lb[I0 + m][j] * xj;
      }
#pragma unroll
      for (int m = 0; m < 8; ++m) spart[(w * 8 + m) * 64 + t] = sv[m];
      __syncthreads();
      if (w == 0) {
        double sv2[8];
#pragma unroll
        for (int m = 0; m < 8; ++m)
          sv2[m] = spart[m * 64 + t] + spart[(8 + m) * 64 + t] +
                   spart[(16 + m) * 64 + t] + spart[(24 + m) * 64 + t];
#pragma unroll
        for (int m = 0; m < 8; ++m) {
          int i = I0 + m;
          double x = (((i == t) ? 1.0 : 0.0) - sv2[m]) * Ldi[i];
#pragma unroll
          for (int mm = m + 1; mm < 8; ++mm) sv2[mm] += Lb[I0 + mm][i] * x;
          Xs[i][t] = x;
        }
      }
      __syncthreads();
    }
    // publish X (wave-split, coalesced agent-scope stores)
#pragma unroll 1
    for (int ii = 0; ii < 16; ++ii) {
      int i = w * 16 + ii;
      __hip_atomic_store(&Xg[i * KK + t], Xs[i][t], __ATOMIC_RELAXED,
                         __HIP_MEMORY_SCOPE_AGENT);
    }
    __syncthreads();                                  // drains stores (vmcnt)
    if (tid == 0) {
      __hip_atomic_store(ld2g, ld2, __ATOMIC_RELAXED, __HIP_MEMORY_SCOPE_AGENT);
      __threadfence();
      __hip_atomic_store(flg, 1, __ATOMIC_RELEASE, __HIP_MEMORY_SCOPE_AGENT);
    }
  }
}

extern "C" void kernel_launch(void* const* d_in, const int* in_sizes, int n_in,
                              void* d_out, int out_size, void* d_ws, size_t ws_size,
                              hipStream_t stream) {
  (void)in_sizes; (void)n_in; (void)out_size; (void)ws_size;
  const float* mu = (const float*)d_in[0];
  const int* labels = (const int*)d_in[1];
  const float* cov = (const float*)d_in[2];
  float* out = (float*)d_out;
  char* ws = (char*)d_ws;

  // zero G+gsum+gcount+cntr+flg+done; gfirst -> 0x7f7f7f7f (acts as +inf for atomicMin)
  hipMemsetAsync(ws, 0, OFF_GFST, stream);
  hipMemsetAsync(ws + OFF_GFST, 0x7f, CC * sizeof(int), stream);

  k_all<<<NGBLK + CC + 1, 256, 0, stream>>>(mu, labels, cov, out, ws);
}